// Round 1
// baseline (581.392 us; speedup 1.0000x reference)
//
#include <hip/hip_runtime.h>

// out = X[8192x4096] @ W^T, W[4096x4096] = scatter_add(values at (row,col)), row_ids sorted.
// R4: GEMM rebuilt as 256x256-tile / 8-wave / 512-thread kernel with:
//   - 4-deep circular LDS pipeline (4 bufs x BK=32 x {A,B} = 128 KiB)
//   - counted vmcnt(8) gates + raw s_barrier (loads stay in flight across barriers; T3+T4)
//   - LDS XOR swizzle (block ^= row&7 on 16B granules) via pre-swizzled global source
//     for global_load_lds + swizzled ds_read offsets (T2; kills the 3.4e7 bank conflicts)
//   - s_setprio(1) around the MFMA cluster (T5)
// Preprocessing (row_start / build_w / cvt) unchanged from R3.

#define M_DIM 8192
#define K_DIM 4096
#define N_DIM 4096
#define NNZ   4194304
#define FXSCALE 1048576.0f          // 2^20 fixed-point scale
#define FXINV  (1.0f / 1048576.0f)

#define BK 32
#define NT (K_DIM / BK)             // 128 K-tiles
#define TILE_US (256 * BK)          // 8192 ushorts = 16 KB per tile buffer

typedef __bf16 bf16x8 __attribute__((ext_vector_type(8)));
typedef float  floatx4 __attribute__((ext_vector_type(4)));
typedef unsigned short ushort8 __attribute__((ext_vector_type(8)));

__device__ __forceinline__ unsigned short f32_to_bf16(float f) {
  unsigned int u = __float_as_uint(f);
  u += 0x7FFFu + ((u >> 16) & 1u);   // round-to-nearest-even
  return (unsigned short)(u >> 16);
}

__device__ __forceinline__ void async_copy16(const void* g, void* l) {
  __builtin_amdgcn_global_load_lds(
      (const __attribute__((address_space(1))) void*)g,
      (__attribute__((address_space(3))) void*)l,
      16, 0, 0);
}

// row_start[r] = lower_bound(rows, r); covers r in [0, N_DIM] exactly once.
__global__ void row_start_kernel(const int* __restrict__ rows,
                                 int* __restrict__ row_start) {
  int i = blockIdx.x * blockDim.x + threadIdx.x;
  if (i > NNZ) return;
  int cur  = (i < NNZ) ? rows[i] : N_DIM;
  int prev = (i > 0) ? rows[i - 1] : -1;
  for (int r = prev + 1; r <= cur; ++r) row_start[r] = i;
}

// One block per W row: dense row in LDS as 2^20 fixed-point ints (native
// ds_add_u32 atomics), then emit bf16.
__global__ __launch_bounds__(256) void build_w_kernel(
    const float* __restrict__ vals,
    const int* __restrict__ cols,
    const int* __restrict__ row_start,
    unsigned short* __restrict__ Wb) {
  __shared__ int wrow[K_DIM];  // 16KB

  const int r = blockIdx.x;
  for (int i = threadIdx.x; i < K_DIM; i += 256) wrow[i] = 0;
  __syncthreads();

  const int start = row_start[r];
  const int end   = row_start[r + 1];
  for (int i = start + threadIdx.x; i < end; i += 256)
    atomicAdd(&wrow[cols[i]], (int)lrintf(vals[i] * FXSCALE));
  __syncthreads();

  ushort8* dst = (ushort8*)(Wb + (size_t)r * K_DIM);
  for (int i = threadIdx.x; i < K_DIM / 8; i += 256) {
    const int* s = &wrow[i * 8];
    ushort8 o;
#pragma unroll
    for (int j = 0; j < 8; j++) o[j] = f32_to_bf16((float)s[j] * FXINV);
    dst[i] = o;
  }
}

__global__ void cvt_kernel(const float4* __restrict__ in,
                           ushort4* __restrict__ out, int n4) {
  int i = blockIdx.x * blockDim.x + threadIdx.x;
  if (i < n4) {
    float4 v = in[i];
    ushort4 o;
    o.x = f32_to_bf16(v.x);
    o.y = f32_to_bf16(v.y);
    o.z = f32_to_bf16(v.z);
    o.w = f32_to_bf16(v.w);
    out[i] = o;
  }
}

// C[M,N] = A[M,K] * B[N,K]^T
// 256x256 block tile, 8 waves (2Mx4N), per-wave 128x64 output = acc[8][4] of 16x16 frags.
// LDS swizzle: 16B block at logical (row, q) lives at physical block
//   b = (row*4 + q) ^ (row & 7)   (bijective; consecutive 8 lanes -> 8 distinct bank groups)
// Staging thread p (=tid) therefore loads logical (sr, sq) with
//   sr = ((p>>3)<<1) | (((p>>2)^(p>>4))&1),  sq = (p&3) ^ (sr&3)
// so that the linear global_load_lds write places it at its swizzled slot.
__global__ __launch_bounds__(512, 2) void gemm_bt(
    const unsigned short* __restrict__ A,
    const unsigned short* __restrict__ B,
    float* __restrict__ C) {
  __shared__ unsigned short As[4 * TILE_US];  // 64 KB
  __shared__ unsigned short Bs[4 * TILE_US];  // 64 KB

  const int tid  = threadIdx.x;
  const int wid  = tid >> 6;
  const int lane = tid & 63;
  const int quad = lane >> 4;
  const int l16  = lane & 15;

  const int m0 = blockIdx.y * 256;
  const int n0 = blockIdx.x * 256;
  const int wm = (wid >> 2) * 128;   // wave M offset (2 rows of waves)
  const int wn = (wid & 3) * 64;     // wave N offset (4 cols of waves)

  // ---- staging source mapping (inverse swizzle) ----
  const int p  = tid;                              // physical 16B-slot index (128 rows x 4)
  const int sr = ((p >> 3) << 1) | (((p >> 2) ^ (p >> 4)) & 1);  // logical row 0..127
  const int sq = (p & 3) ^ (sr & 3);                             // logical 16B block 0..3

  const unsigned short* Ag0 = A + (size_t)(m0 + sr) * K_DIM + sq * 8;
  const unsigned short* Ag1 = Ag0 + (size_t)128 * K_DIM;
  const unsigned short* Bg0 = B + (size_t)(n0 + sr) * K_DIM + sq * 8;
  const unsigned short* Bg1 = Bg0 + (size_t)128 * K_DIM;

  unsigned short* Al0 = &As[(wid * 16) * BK] + lane * 8;  // wave-linear dest, lane0 = base
  unsigned short* Al1 = Al0 + 128 * BK;
  unsigned short* Bl0 = &Bs[(wid * 16) * BK] + lane * 8;
  unsigned short* Bl1 = Bl0 + 128 * BK;

  // ---- swizzled ds_read offsets (ushort units), constant over K-loop ----
  int offA[8], offB[4];
#pragma unroll
  for (int t = 0; t < 8; ++t) {
    const int row = wm + t * 16 + l16;
    offA[t] = ((row * 4 + quad) ^ (row & 7)) << 3;
  }
#pragma unroll
  for (int t = 0; t < 4; ++t) {
    const int row = wn + t * 16 + l16;
    offB[t] = ((row * 4 + quad) ^ (row & 7)) << 3;
  }

  floatx4 acc[8][4];
#pragma unroll
  for (int i = 0; i < 8; i++)
#pragma unroll
    for (int j = 0; j < 4; j++) acc[i][j] = (floatx4){0.f, 0.f, 0.f, 0.f};

#define STAGE(t_) do {                                   \
    const int b_  = (t_) & 3;                            \
    const int kt_ = (t_) * BK;                           \
    async_copy16(Ag0 + kt_, Al0 + b_ * TILE_US);         \
    async_copy16(Ag1 + kt_, Al1 + b_ * TILE_US);         \
    async_copy16(Bg0 + kt_, Bl0 + b_ * TILE_US);         \
    async_copy16(Bg1 + kt_, Bl1 + b_ * TILE_US);         \
  } while (0)

#define COMPUTE(t_) do {                                                      \
    const unsigned short* Ab_ = &As[((t_) & 3) * TILE_US];                    \
    const unsigned short* Bb_ = &Bs[((t_) & 3) * TILE_US];                    \
    bf16x8 af_[8], bf_[4];                                                    \
    _Pragma("unroll")                                                         \
    for (int i_ = 0; i_ < 8; ++i_) af_[i_] = *(const bf16x8*)(Ab_ + offA[i_]);\
    _Pragma("unroll")                                                         \
    for (int j_ = 0; j_ < 4; ++j_) bf_[j_] = *(const bf16x8*)(Bb_ + offB[j_]);\
    __builtin_amdgcn_s_setprio(1);                                            \
    _Pragma("unroll")                                                         \
    for (int i_ = 0; i_ < 8; ++i_)                                            \
      _Pragma("unroll")                                                       \
      for (int j_ = 0; j_ < 4; ++j_)                                          \
        acc[i_][j_] = __builtin_amdgcn_mfma_f32_16x16x32_bf16(                \
            af_[i_], bf_[j_], acc[i_][j_], 0, 0, 0);                          \
    __builtin_amdgcn_s_setprio(0);                                            \
  } while (0)

  // prologue: 3 K-tiles in flight
  STAGE(0);
  STAGE(1);
  STAGE(2);

  // main loop: gate vmcnt(8) => tile t's 4 loads landed (t+1,t+2 may be in flight);
  // barrier => every wave's loads for t landed AND every wave finished tile t-1,
  // so staging t+3 into buf[(t+3)&3] == buf[(t-1)&3] is race-free.
  for (int t = 0; t < NT - 3; ++t) {
    asm volatile("s_waitcnt vmcnt(8)" ::: "memory");
    asm volatile("s_barrier" ::: "memory");
    STAGE(t + 3);
    COMPUTE(t);
  }
  asm volatile("s_waitcnt vmcnt(8)" ::: "memory");
  asm volatile("s_barrier" ::: "memory");
  COMPUTE(NT - 3);
  asm volatile("s_waitcnt vmcnt(4)" ::: "memory");
  asm volatile("s_barrier" ::: "memory");
  COMPUTE(NT - 2);
  asm volatile("s_waitcnt vmcnt(0)" ::: "memory");
  asm volatile("s_barrier" ::: "memory");
  COMPUTE(NT - 1);

#undef STAGE
#undef COMPUTE

  // epilogue: C/D layout col = lane&15, row = quad*4 + r (verified convention)
#pragma unroll
  for (int tm = 0; tm < 8; tm++) {
#pragma unroll
    for (int r = 0; r < 4; r++) {
      const int row = m0 + wm + tm * 16 + quad * 4 + r;
      float* Cp = C + (size_t)row * N_DIM + n0 + wn + l16;
#pragma unroll
      for (int tn = 0; tn < 4; tn++) Cp[tn * 16] = acc[tm][tn][r];
    }
  }
}

extern "C" void kernel_launch(void* const* d_in, const int* in_sizes, int n_in,
                              void* d_out, int out_size, void* d_ws, size_t ws_size,
                              hipStream_t stream) {
  const float* x       = (const float*)d_in[0];
  const float* values  = (const float*)d_in[1];
  const int*   col_idx = (const int*)d_in[2];
  const int*   row_ids = (const int*)d_in[3];
  float* out = (float*)d_out;

  // ws layout: [0,32MB) W bf16 | [32MB,96MB) X bf16 | [96MB,+16.4KB) row_start
  unsigned short* Wb = (unsigned short*)d_ws;
  unsigned short* Xb = (unsigned short*)((char*)d_ws + ((size_t)32 << 20));
  int* row_start     = (int*)((char*)d_ws + ((size_t)96 << 20));

  const int x4 = M_DIM * K_DIM / 4;

  row_start_kernel<<<(NNZ + 256) / 256, 256, 0, stream>>>(row_ids, row_start);
  cvt_kernel<<<(x4 + 255) / 256, 256, 0, stream>>>((const float4*)x, (ushort4*)Xb, x4);
  build_w_kernel<<<N_DIM, 256, 0, stream>>>(values, col_idx, row_start, Wb);

  dim3 grid(N_DIM / 256, M_DIM / 256);  // (16, 32)
  gemm_bt<<<grid, 512, 0, stream>>>(Xb, Wb, out);
}

// Round 2
// 466.879 us; speedup vs baseline: 1.2453x; 1.2453x over previous
//
#include <hip/hip_runtime.h>

// out = X[8192x4096] @ W^T, W[4096x4096] = scatter_add(values at (row,col)), row_ids sorted.
// R5: faithful port of the verified 256^2 8-phase template (m201 structure):
//   BM=BN=256, BK=64, 8 waves (2Mx4N), 512 thr, LDS 2buf x (A 32KB + B 32KB) = 128KB.
//   Per phase: ds_read subtile || stage 1 half-tile (2 x global_load_lds) -> s_barrier
//   -> lgkmcnt(0)+sched_barrier -> setprio(1) -> 16 MFMA -> setprio(0) -> s_barrier.
//   vmcnt(6) ONLY at phases 4/8 (3 half-tiles in flight). Same-buffer staging is
//   race-free via region death: wave frags remapped so A[0:128) dies after ph1,
//   B[128:256) after ph2, A[128:256) after ph3; each stage targets a dead region.
//   LDS bank swizzle: 16B block b -> b ^ (row&7), applied as pre-swizzled global
//   source (linear gload_lds dest) + swizzled ds_read offsets. XCD-aware wg swizzle.
// Preprocessing (row_start / build_w / cvt) unchanged from R3.

#define M_DIM 8192
#define K_DIM 4096
#define N_DIM 4096
#define NNZ   4194304
#define FXSCALE 1048576.0f
#define FXINV  (1.0f / 1048576.0f)

#define BKT 64                 // K per tile
#define NTIL (K_DIM / BKT)     // 64 K-tiles
#define ABUF 16384             // ushorts per A/B buffer (256 rows x 64 K)

typedef __bf16 bf16x8 __attribute__((ext_vector_type(8)));
typedef float  floatx4 __attribute__((ext_vector_type(4)));
typedef unsigned short ushort8 __attribute__((ext_vector_type(8)));

__device__ __forceinline__ unsigned short f32_to_bf16(float f) {
  unsigned int u = __float_as_uint(f);
  u += 0x7FFFu + ((u >> 16) & 1u);
  return (unsigned short)(u >> 16);
}

__device__ __forceinline__ void async_copy16(const void* g, void* l) {
  __builtin_amdgcn_global_load_lds(
      (const __attribute__((address_space(1))) void*)g,
      (__attribute__((address_space(3))) void*)l,
      16, 0, 0);
}

__global__ void row_start_kernel(const int* __restrict__ rows,
                                 int* __restrict__ row_start) {
  int i = blockIdx.x * blockDim.x + threadIdx.x;
  if (i > NNZ) return;
  int cur  = (i < NNZ) ? rows[i] : N_DIM;
  int prev = (i > 0) ? rows[i - 1] : -1;
  for (int r = prev + 1; r <= cur; ++r) row_start[r] = i;
}

__global__ __launch_bounds__(256) void build_w_kernel(
    const float* __restrict__ vals,
    const int* __restrict__ cols,
    const int* __restrict__ row_start,
    unsigned short* __restrict__ Wb) {
  __shared__ int wrow[K_DIM];

  const int r = blockIdx.x;
  for (int i = threadIdx.x; i < K_DIM; i += 256) wrow[i] = 0;
  __syncthreads();

  const int start = row_start[r];
  const int end   = row_start[r + 1];
  for (int i = start + threadIdx.x; i < end; i += 256)
    atomicAdd(&wrow[cols[i]], (int)lrintf(vals[i] * FXSCALE));
  __syncthreads();

  ushort8* dst = (ushort8*)(Wb + (size_t)r * K_DIM);
  for (int i = threadIdx.x; i < K_DIM / 8; i += 256) {
    const int* s = &wrow[i * 8];
    ushort8 o;
#pragma unroll
    for (int j = 0; j < 8; j++) o[j] = f32_to_bf16((float)s[j] * FXINV);
    dst[i] = o;
  }
}

__global__ void cvt_kernel(const float4* __restrict__ in,
                           ushort4* __restrict__ out, int n4) {
  int i = blockIdx.x * blockDim.x + threadIdx.x;
  if (i < n4) {
    float4 v = in[i];
    ushort4 o;
    o.x = f32_to_bf16(v.x);
    o.y = f32_to_bf16(v.y);
    o.z = f32_to_bf16(v.z);
    o.w = f32_to_bf16(v.w);
    out[i] = o;
  }
}

// ---------------- 256x256 8-phase GEMM ----------------
#define BAR()   asm volatile("s_barrier" ::: "memory")
#define LGKM0() do { asm volatile("s_waitcnt lgkmcnt(0)" ::: "memory"); \
                     __builtin_amdgcn_sched_barrier(0); } while (0)
#define VMW6()  asm volatile("s_waitcnt vmcnt(6)" ::: "memory")
#define VMW0()  asm volatile("s_waitcnt vmcnt(0)" ::: "memory")

// stage one 16KB half-tile (128 rows x 64 K bf16): 2 global_load_lds per thread.
// LDS dest is linear (base + tid*16B); global source is inverse-swizzled so that
// physical block (tid&7) holds logical block (tid&7)^(row&7).
#define STAGEH(Gb_, Lb_, h_, kt_) do {                                          \
  async_copy16((Gb_) + (size_t)((h_)*128 +      srow) * K_DIM + (kt_),          \
               (Lb_) + (h_)*8192 +        tid * 8);                             \
  async_copy16((Gb_) + (size_t)((h_)*128 + 64 + srow) * K_DIM + (kt_),          \
               (Lb_) + (h_)*8192 + 4096 + tid * 8);                             \
} while (0)

#define RD_A(Ab_, mb_) do {                                                     \
  _Pragma("unroll")                                                             \
  for (int m_ = 0; m_ < 4; ++m_) {                                              \
    af[m_][0] = *(const bf16x8*)((Ab_) + offA[(mb_) + m_][0]);                  \
    af[m_][1] = *(const bf16x8*)((Ab_) + offA[(mb_) + m_][1]);                  \
  }                                                                             \
} while (0)

#define RD_B(Bb_, nb_) do {                                                     \
  _Pragma("unroll")                                                             \
  for (int n_ = 0; n_ < 2; ++n_) {                                              \
    bf[(nb_) + n_][0] = *(const bf16x8*)((Bb_) + offB[(nb_) + n_][0]);          \
    bf[(nb_) + n_][1] = *(const bf16x8*)((Bb_) + offB[(nb_) + n_][1]);          \
  }                                                                             \
} while (0)

#define MM(mb_, nb_) do {                                                       \
  __builtin_amdgcn_s_setprio(1);                                                \
  _Pragma("unroll")                                                             \
  for (int m_ = 0; m_ < 4; ++m_)                                                \
    _Pragma("unroll")                                                           \
    for (int n_ = 0; n_ < 2; ++n_) {                                            \
      acc[(mb_) + m_][(nb_) + n_] = __builtin_amdgcn_mfma_f32_16x16x32_bf16(    \
          af[m_][0], bf[(nb_) + n_][0], acc[(mb_) + m_][(nb_) + n_], 0, 0, 0);  \
      acc[(mb_) + m_][(nb_) + n_] = __builtin_amdgcn_mfma_f32_16x16x32_bf16(    \
          af[m_][1], bf[(nb_) + n_][1], acc[(mb_) + m_][(nb_) + n_], 0, 0, 0);  \
    }                                                                           \
  __builtin_amdgcn_s_setprio(0);                                                \
} while (0)

__global__ __launch_bounds__(512, 2) void gemm_bt(
    const unsigned short* __restrict__ A,
    const unsigned short* __restrict__ B,
    float* __restrict__ C) {
  // LDS[0]=A buf0, LDS[1]=B buf0, LDS[2]=A buf1, LDS[3]=B buf1  (128 KB)
  __shared__ __attribute__((aligned(16))) unsigned short LDS[4][ABUF];

  const int tid  = threadIdx.x;
  const int wid  = tid >> 6;
  const int lane = tid & 63;
  const int quad = lane >> 4;
  const int l16  = lane & 15;
  const int mh   = wid >> 2;   // wave M-half (0/1)
  const int w32  = wid & 3;    // wave N-column (0..3)

  // XCD-aware swizzle: 512 wgs, 64 contiguous per XCD.
  int wg = blockIdx.x;
  wg = (wg & 7) * 64 + (wg >> 3);
  const int n0 = (wg & 15) * 256;
  const int m0 = (wg >> 4) * 256;

  // staging constants: thread t writes physical 16B block (t&7) of row (t>>3)
  // within a 64-row chunk; it must FETCH logical block (t&7)^(row&7).
  const int srow = tid >> 3;
  const int sblk = ((tid & 7) ^ ((tid >> 3) & 7)) * 8;
  const unsigned short* Abase = A + (size_t)m0 * K_DIM + sblk;
  const unsigned short* Bbase = B + (size_t)n0 * K_DIM + sblk;

  // fragment row map (contiguous death regions):
  //   A frags 0-3 -> rows mh*64+{0,16,32,48}         (region [0,128): dies ph1)
  //   A frags 4-7 -> rows 128+mh*64+{0,16,32,48}     (region [128,256): dies ph3)
  //   B frags 0-1 -> rows w32*32+{0,16}              (region [0,128): dies ph1)
  //   B frags 2-3 -> rows 128+w32*32+{0,16}          (region [128,256): dies ph2)
  // ds_read offset (ushorts): row*64 + (((h*4+quad) ^ (row&7)) * 8)
  int offA[8][2], offB[4][2];
#pragma unroll
  for (int m = 0; m < 8; ++m) {
    const int r = (m < 4 ? mh * 64 + m * 16 : 128 + mh * 64 + (m - 4) * 16) + l16;
#pragma unroll
    for (int h = 0; h < 2; ++h)
      offA[m][h] = r * 64 + (((h * 4 + quad) ^ (r & 7)) * 8);
  }
#pragma unroll
  for (int n = 0; n < 4; ++n) {
    const int r = (n < 2 ? w32 * 32 + n * 16 : 128 + w32 * 32 + (n - 2) * 16) + l16;
#pragma unroll
    for (int h = 0; h < 2; ++h)
      offB[n][h] = r * 64 + (((h * 4 + quad) ^ (r & 7)) * 8);
  }

  floatx4 acc[8][4];
#pragma unroll
  for (int i = 0; i < 8; i++)
#pragma unroll
    for (int j = 0; j < 4; j++) acc[i][j] = (floatx4){0.f, 0.f, 0.f, 0.f};

  bf16x8 af[4][2], bf[4][2];

  unsigned short* A0L = &LDS[0][0];
  unsigned short* B0L = &LDS[1][0];
  unsigned short* A1L = &LDS[2][0];
  unsigned short* B1L = &LDS[3][0];

  // ---- prologue: tile0 (4 halves) + tile1 (A0,B0,A1) = 7 stages = 14 loads ----
  STAGEH(Abase, A0L, 0, 0);
  STAGEH(Bbase, B0L, 0, 0);
  STAGEH(Abase, A0L, 1, 0);
  STAGEH(Bbase, B0L, 1, 0);
  STAGEH(Abase, A1L, 0, BKT);
  STAGEH(Bbase, B1L, 0, BKT);
  STAGEH(Abase, A1L, 1, BKT);
  VMW6();   // tile0 fully landed; tile1's 3 halves still in flight
  BAR();

  // ---- main loop: 2 K-tiles per iteration, 8 phases ----
  for (int i = 0; i < NTIL / 2 - 1; ++i) {
    const int ktE = (2 * i) * BKT;
    // ======== tile E (buf0) ========
    // ph1
    RD_A(A0L, 0); RD_B(B0L, 0);
    STAGEH(Bbase, B1L, 1, ktE + BKT);        // B1(E+1) -> buf1 B[128:256)
    BAR(); LGKM0();
    MM(0, 0);
    BAR();
    // ph2
    RD_B(B0L, 2);
    STAGEH(Abase, A0L, 0, ktE + 2 * BKT);    // A0(E+2) -> buf0 A[0:128) (dead ph1)
    BAR(); LGKM0();
    MM(0, 2);
    BAR();
    // ph3
    RD_A(A0L, 4);
    STAGEH(Bbase, B0L, 0, ktE + 2 * BKT);    // B0(E+2) -> buf0 B[0:128) (dead ph1)
    BAR(); LGKM0();
    MM(4, 0);
    BAR();
    // ph4
    STAGEH(Abase, A0L, 1, ktE + 2 * BKT);    // A1(E+2) -> buf0 A[128:256) (dead ph3)
    BAR();
    MM(4, 2);
    VMW6();                                   // tile E+1 fully landed
    BAR();
    // ======== tile O = E+1 (buf1) ========
    // ph1
    RD_A(A1L, 0); RD_B(B1L, 0);
    STAGEH(Bbase, B0L, 1, ktE + 2 * BKT);    // B1(E+2) -> buf0 B[128:256) (dead E.ph2)
    BAR(); LGKM0();
    MM(0, 0);
    BAR();
    // ph2
    RD_B(B1L, 2);
    STAGEH(Abase, A1L, 0, ktE + 3 * BKT);    // A0(E+3) -> buf1 A[0:128) (dead ph1)
    BAR(); LGKM0();
    MM(0, 2);
    BAR();
    // ph3
    RD_A(A1L, 4);
    STAGEH(Bbase, B1L, 0, ktE + 3 * BKT);    // B0(E+3) -> buf1 B[0:128) (dead ph1)
    BAR(); LGKM0();
    MM(4, 0);
    BAR();
    // ph4
    STAGEH(Abase, A1L, 1, ktE + 3 * BKT);    // A1(E+3) -> buf1 A[128:256) (dead ph3)
    BAR();
    MM(4, 2);
    VMW6();                                   // tile E+2 fully landed
    BAR();
  }

  // ---- peeled last iteration: tiles NTIL-2 (buf0), NTIL-1 (buf1) ----
  {
    const int ktE = (NTIL - 2) * BKT;
    // tile NTIL-2
    RD_A(A0L, 0); RD_B(B0L, 0);
    STAGEH(Bbase, B1L, 1, ktE + BKT);        // B1(NTIL-1)
    BAR(); LGKM0();
    MM(0, 0);
    BAR();
    RD_B(B0L, 2);
    BAR(); LGKM0();
    MM(0, 2);
    BAR();
    RD_A(A0L, 4);
    BAR(); LGKM0();
    MM(4, 0);
    BAR();
    MM(4, 2);
    VMW0();                                   // drain: tile NTIL-1 landed
    BAR();
    // tile NTIL-1 (no staging)
    RD_A(A1L, 0); RD_B(B1L, 0);
    BAR(); LGKM0();
    MM(0, 0);
    BAR();
    RD_B(B1L, 2);
    BAR(); LGKM0();
    MM(0, 2);
    BAR();
    RD_A(A1L, 4);
    BAR(); LGKM0();
    MM(4, 0);
    BAR();
    MM(4, 2);
  }

  // ---- epilogue: C/D layout col = lane&15, row = quad*4 + r ----
#pragma unroll
  for (int m = 0; m < 8; m++) {
    const int mrow = (m < 4 ? mh * 64 + m * 16 : 128 + mh * 64 + (m - 4) * 16);
#pragma unroll
    for (int r = 0; r < 4; r++) {
      const int row = m0 + mrow + quad * 4 + r;
      float* Cp = C + (size_t)row * N_DIM + n0 + l16;
#pragma unroll
      for (int n = 0; n < 4; n++) {
        const int ncol = (n < 2 ? w32 * 32 + n * 16 : 128 + w32 * 32 + (n - 2) * 16);
        Cp[ncol] = acc[m][n][r];
      }
    }
  }
}

extern "C" void kernel_launch(void* const* d_in, const int* in_sizes, int n_in,
                              void* d_out, int out_size, void* d_ws, size_t ws_size,
                              hipStream_t stream) {
  const float* x       = (const float*)d_in[0];
  const float* values  = (const float*)d_in[1];
  const int*   col_idx = (const int*)d_in[2];
  const int*   row_ids = (const int*)d_in[3];
  float* out = (float*)d_out;

  unsigned short* Wb = (unsigned short*)d_ws;
  unsigned short* Xb = (unsigned short*)((char*)d_ws + ((size_t)32 << 20));
  int* row_start     = (int*)((char*)d_ws + ((size_t)96 << 20));

  const int x4 = M_DIM * K_DIM / 4;

  row_start_kernel<<<(NNZ + 256) / 256, 256, 0, stream>>>(row_ids, row_start);
  cvt_kernel<<<(x4 + 255) / 256, 256, 0, stream>>>((const float4*)x, (ushort4*)Xb, x4);
  build_w_kernel<<<N_DIM, 256, 0, stream>>>(values, col_idx, row_start, Wb);

  gemm_bt<<<dim3(512), 512, 0, stream>>>(Xb, Wb, out);
}